// Round 1
// baseline (151.363 us; speedup 1.0000x reference)
//
#include <hip/hip_runtime.h>

// FreqLinear: out[256,8192] = X[256,4096] @ W^T + bias, W synthesized from
// 8-mode DCT codes. Restructured as out = Y2 @ float(idx)^T + corr[m] + bias[o]
// with Y2[m, j*8+k] = s[k] * sum_t x[m,16j+t]*B[k,t]  (bf16, 1 MB, in d_ws)
//      corr[m]      = sum_{j,k} y[m,j,k]*c_min[k]     (fp32, in d_ws)
// K = 2048 (=256 blocks * 8 modes), contiguous in idx memory per output col.

typedef __attribute__((ext_vector_type(8))) short bf16x8;   // 8 bf16 = 4 VGPRs
typedef __attribute__((ext_vector_type(4))) float f32x4;

#define K_TOT 2048
#define N_TOT 8192
#define NT    32          // output cols per workgroup
#define BK    32          // K per step (one MFMA k-chunk)
#define NSTEP (K_TOT / BK)

__device__ __forceinline__ unsigned short f2bf(float f) {
    unsigned u = __float_as_uint(f);
    u += 0x7FFFu + ((u >> 16) & 1u);   // round-nearest-even
    return (unsigned short)(u >> 16);
}

// ---------------- Kernel A: build Y2 (bf16) and corr (fp32) ----------------
// grid 256 (one block per m-row), block 256 (one thread per 16-block j)
__global__ __launch_bounds__(256) void prep_kernel(
    const float* __restrict__ x, const float* __restrict__ c_min,
    const float* __restrict__ c_range, unsigned short* __restrict__ Y2,
    float* __restrict__ corr)
{
    __shared__ float Bk[8][16];
    __shared__ float scmin[8];
    __shared__ float ss[8];
    __shared__ float red[4];
    const int tid = threadIdx.x;
    const int m = blockIdx.x;
    if (tid < 128) {
        int k = tid >> 4, t = tid & 15;
        float v = cosf(3.14159265358979f * (t + 0.5f) * (float)k / 16.0f)
                  * 0.353553390593274f;                 // sqrt(2/16)
        if (k == 0) v *= 0.707106781186548f;            // 1/sqrt(2)
        Bk[k][t] = v;
    }
    if (tid < 8) {
        scmin[tid] = c_min[tid];
        ss[tid] = c_range[tid] * (1.0f / 255.0f);
    }
    __syncthreads();

    const float* xp = x + (long)m * 4096 + tid * 16;
    float xs[16];
#pragma unroll
    for (int q = 0; q < 4; ++q) {
        float4 v = *(const float4*)(xp + q * 4);
        xs[q * 4 + 0] = v.x; xs[q * 4 + 1] = v.y;
        xs[q * 4 + 2] = v.z; xs[q * 4 + 3] = v.w;
    }
    float partial = 0.0f;
    unsigned short yo[8];
#pragma unroll
    for (int k = 0; k < 8; ++k) {
        float y = 0.0f;
#pragma unroll
        for (int t = 0; t < 16; ++t) y += xs[t] * Bk[k][t];
        partial += y * scmin[k];
        yo[k] = f2bf(y * ss[k]);
    }
    uint4 pk;
    pk.x = (unsigned)yo[0] | ((unsigned)yo[1] << 16);
    pk.y = (unsigned)yo[2] | ((unsigned)yo[3] << 16);
    pk.z = (unsigned)yo[4] | ((unsigned)yo[5] << 16);
    pk.w = (unsigned)yo[6] | ((unsigned)yo[7] << 16);
    *(uint4*)(Y2 + (long)m * K_TOT + tid * 8) = pk;

    // block-reduce partial -> corr[m]
#pragma unroll
    for (int off = 32; off > 0; off >>= 1)
        partial += __shfl_down(partial, off, 64);
    if ((tid & 63) == 0) red[tid >> 6] = partial;
    __syncthreads();
    if (tid == 0) corr[m] = red[0] + red[1] + red[2] + red[3];
}

// ---------------- Kernel B: out = Y2 @ float(idx)^T + corr + bias ----------
// grid 256 wgs (o-tile of 32 cols each), block 512 = 8 waves.
// wave w owns m-rows [32w, 32w+32); A-frags straight from global (L2-hot);
// idx staged+dequantized into double-buffered padded LDS (shared by 8 waves).
__global__ __launch_bounds__(512) void gemm_kernel(
    const unsigned short* __restrict__ Y2, const int* __restrict__ idx,
    const float* __restrict__ bias, const float* __restrict__ corr,
    float* __restrict__ out)
{
    __shared__ unsigned short Blds[2][32][40];   // pad 32->40: frag reads 2-way max

    const int tid  = threadIdx.x;
    const int wave = tid >> 6;
    const int lane = tid & 63;
    const int o0   = blockIdx.x * NT;
    const int mw   = wave * 32;

    // B staging: thread -> (col o0+sn, 2 ints at k-offset sc*2)
    const int sn = tid >> 4;      // 0..31
    const int sc = tid & 15;      // 0..15
    const long sBase = (long)(o0 + sn) * K_TOT + sc * 2;

    // fragment coords (16x16x32 layout: row/col = lane&15, k = (lane>>4)*8+j)
    const int fr = lane & 15;
    const int fq = lane >> 4;
    const int kcol = fq * 8;

    const unsigned short* aBase0 = Y2 + (long)(mw + fr) * K_TOT + kcol;
    const unsigned short* aBase1 = aBase0 + 16 * K_TOT;

    f32x4 acc00 = {0.f,0.f,0.f,0.f}, acc01 = {0.f,0.f,0.f,0.f};
    f32x4 acc10 = {0.f,0.f,0.f,0.f}, acc11 = {0.f,0.f,0.f,0.f};

    // stage step 0
    {
        int2 v = *(const int2*)(idx + sBase);
        unsigned p = (unsigned)f2bf((float)v.x) | ((unsigned)f2bf((float)v.y) << 16);
        *(unsigned*)&Blds[0][sn][sc * 2] = p;
    }
    bf16x8 a0 = *(const bf16x8*)(aBase0);
    bf16x8 a1 = *(const bf16x8*)(aBase1);
    __syncthreads();

    for (int kc = 0; kc < NSTEP; ++kc) {
        const int cur = kc & 1;
        bf16x8 na0, na1;
        if (kc + 1 < NSTEP) {
            // prefetch next B into other buffer + next A into regs
            int2 v = *(const int2*)(idx + sBase + (kc + 1) * BK);
            unsigned p = (unsigned)f2bf((float)v.x) | ((unsigned)f2bf((float)v.y) << 16);
            *(unsigned*)&Blds[cur ^ 1][sn][sc * 2] = p;
            na0 = *(const bf16x8*)(aBase0 + (kc + 1) * BK);
            na1 = *(const bf16x8*)(aBase1 + (kc + 1) * BK);
        }
        bf16x8 b0 = *(const bf16x8*)&Blds[cur][fr][kcol];
        bf16x8 b1 = *(const bf16x8*)&Blds[cur][fr + 16][kcol];
        acc00 = __builtin_amdgcn_mfma_f32_16x16x32_bf16(a0, b0, acc00, 0, 0, 0);
        acc01 = __builtin_amdgcn_mfma_f32_16x16x32_bf16(a0, b1, acc01, 0, 0, 0);
        acc10 = __builtin_amdgcn_mfma_f32_16x16x32_bf16(a1, b0, acc10, 0, 0, 0);
        acc11 = __builtin_amdgcn_mfma_f32_16x16x32_bf16(a1, b1, acc11, 0, 0, 0);
        if (kc + 1 < NSTEP) { a0 = na0; a1 = na1; }
        __syncthreads();
    }

    // epilogue: D layout col=lane&15, row=(lane>>4)*4+reg  [m89/m91]
    const int col0 = o0 + fr;
    const float bv0 = bias[col0];
    const float bv1 = bias[col0 + 16];
#pragma unroll
    for (int mt = 0; mt < 2; ++mt) {
        const int mrow = mw + mt * 16 + fq * 4;
        const f32x4 aN0 = mt ? acc10 : acc00;
        const f32x4 aN1 = mt ? acc11 : acc01;
#pragma unroll
        for (int r = 0; r < 4; ++r) {
            const float cv = corr[mrow + r];
            const long ro = (long)(mrow + r) * N_TOT;
            out[ro + col0]      = aN0[r] + bv0 + cv;
            out[ro + col0 + 16] = aN1[r] + bv1 + cv;
        }
    }
}

extern "C" void kernel_launch(void* const* d_in, const int* in_sizes, int n_in,
                              void* d_out, int out_size, void* d_ws, size_t ws_size,
                              hipStream_t stream) {
    const float* x       = (const float*)d_in[0];   // [32,8,4096]
    const int*   idx     = (const int*)d_in[1];     // [2097152, 8]
    const float* c_min   = (const float*)d_in[2];   // [8]
    const float* c_range = (const float*)d_in[3];   // [8]
    const float* bias    = (const float*)d_in[4];   // [8192]
    float* out = (float*)d_out;                     // [256, 8192]

    unsigned short* Y2 = (unsigned short*)d_ws;                 // 256*2048 bf16 = 1 MB
    float* corr = (float*)((char*)d_ws + (size_t)256 * K_TOT * 2); // 256 fp32

    prep_kernel<<<256, 256, 0, stream>>>(x, c_min, c_range, Y2, corr);
    gemm_kernel<<<N_TOT / NT, 512, 0, stream>>>(Y2, idx, bias, corr, out);
}

// Round 2
// 148.586 us; speedup vs baseline: 1.0187x; 1.0187x over previous
//
#include <hip/hip_runtime.h>

// FreqLinear restructured: out = Y2 @ float(idx)^T + corr[m] + bias[o]
//   Y2[m, j*8+k] = (c_range[k]/255) * sum_t x[m,16j+t]*B[k,t]   (bf16)
//   corr[m]      = sum_{j,k} y[m,j,k]*c_min[k]                  (fp32)
// K = 2048. Y2 stored in MFMA A-fragment order so gemm A-loads are one
// coalesced dwordx4 per fragment:
//   Y2f[((mg*64 + kc)*64 + lane)*8 + j] = A[m=mg*16+(lane&15)]
//                                          [k=kc*32+(lane>>4)*8+j]
// GEMM: barrier-free. Block = 256 thr = 4 waves; block owns 16 cols x all
// 256 rows (wave w -> rows [64w,64w+64)). B-fragments loaded straight from
// idx (16 rows x 128B contiguous per wave-step), int->bf16 in registers
// (exact: values <=255). B prefetch depth 4 (HBM), A depth 2 (L2-hot).

typedef __attribute__((ext_vector_type(8))) short bf16x8;   // 8 bf16 = 4 VGPRs
typedef __attribute__((ext_vector_type(4))) float f32x4;

#define K_TOT  2048
#define N_TOT  8192
#define KSTEPS 64          // K_TOT / 32
#define DEPTH  4           // B prefetch depth (k-steps in flight)

__device__ __forceinline__ unsigned short f2bf_rn(float f) {
    unsigned u = __float_as_uint(f);
    u += 0x7FFFu + ((u >> 16) & 1u);   // round-nearest-even
    return (unsigned short)(u >> 16);
}

// two ints (0..255) -> exact floats -> packed bf16 pair (truncation exact)
__device__ __forceinline__ unsigned pack2(int a, int b) {
    unsigned ua = __float_as_uint((float)a);
    unsigned ub = __float_as_uint((float)b);
    return __builtin_amdgcn_perm(ub, ua, 0x07060302u);  // {ub.hi16, ua.hi16}
}

__device__ __forceinline__ bf16x8 cvt_bfrag(int4 lo, int4 hi) {
    union { unsigned u[4]; bf16x8 v; } r;
    r.u[0] = pack2(lo.x, lo.y);
    r.u[1] = pack2(lo.z, lo.w);
    r.u[2] = pack2(hi.x, hi.y);
    r.u[3] = pack2(hi.z, hi.w);
    return r.v;
}

// ---------------- Kernel A: build Y2f (bf16, frag order) + corr ------------
// grid 256 (one block per m-row), block 256 (one thread per 16-block j)
__global__ __launch_bounds__(256) void prep_kernel(
    const float* __restrict__ x, const float* __restrict__ c_min,
    const float* __restrict__ c_range, unsigned short* __restrict__ Y2f,
    float* __restrict__ corr)
{
    __shared__ float Bk[8][16];
    __shared__ float scmin[8];
    __shared__ float ss[8];
    __shared__ float red[4];
    const int tid = threadIdx.x;
    const int m = blockIdx.x;
    if (tid < 128) {
        int k = tid >> 4, t = tid & 15;
        float v = cosf(3.14159265358979f * (t + 0.5f) * (float)k / 16.0f)
                  * 0.353553390593274f;                 // sqrt(2/16)
        if (k == 0) v *= 0.707106781186548f;            // 1/sqrt(2)
        Bk[k][t] = v;
    }
    if (tid < 8) {
        scmin[tid] = c_min[tid];
        ss[tid] = c_range[tid] * (1.0f / 255.0f);
    }
    __syncthreads();

    const float* xp = x + (long)m * 4096 + tid * 16;
    float xs[16];
#pragma unroll
    for (int q = 0; q < 4; ++q) {
        float4 v = *(const float4*)(xp + q * 4);
        xs[q * 4 + 0] = v.x; xs[q * 4 + 1] = v.y;
        xs[q * 4 + 2] = v.z; xs[q * 4 + 3] = v.w;
    }
    float partial = 0.0f;
    unsigned short yo[8];
#pragma unroll
    for (int k = 0; k < 8; ++k) {
        float y = 0.0f;
#pragma unroll
        for (int t = 0; t < 16; ++t) y += xs[t] * Bk[k][t];
        partial += y * scmin[k];
        yo[k] = f2bf_rn(y * ss[k]);
    }
    uint4 pk;
    pk.x = (unsigned)yo[0] | ((unsigned)yo[1] << 16);
    pk.y = (unsigned)yo[2] | ((unsigned)yo[3] << 16);
    pk.z = (unsigned)yo[4] | ((unsigned)yo[5] << 16);
    pk.w = (unsigned)yo[6] | ((unsigned)yo[7] << 16);

    // Fragment-order store: this thread covers K = tid*8..tid*8+7
    //   kc = tid>>2, fq = tid&3, mg = m>>4, fr = m&15, lane = fq*16+fr
    {
        const int mg = m >> 4, fr = m & 15, kc = tid >> 2, fq = tid & 3;
        unsigned short* dst = Y2f + ((long)((mg * 64 + kc) * 64) + fq * 16 + fr) * 8;
        *(uint4*)dst = pk;
    }

    // block-reduce partial -> corr[m]
#pragma unroll
    for (int off = 32; off > 0; off >>= 1)
        partial += __shfl_down(partial, off, 64);
    if ((tid & 63) == 0) red[tid >> 6] = partial;
    __syncthreads();
    if (tid == 0) corr[m] = red[0] + red[1] + red[2] + red[3];
}

// ---------------- Kernel B: barrier-free GEMM ------------------------------
// grid 512 (16 cols each), block 256 = 4 waves; wave w -> rows [64w, 64w+64)
__global__ __launch_bounds__(256, 2) void gemm_kernel(
    const unsigned short* __restrict__ Y2f, const int* __restrict__ idx,
    const float* __restrict__ bias, const float* __restrict__ corr,
    float* __restrict__ out)
{
    const int tid  = threadIdx.x;
    const int wave = tid >> 6;
    const int lane = tid & 63;
    const int fr   = lane & 15;     // col within group / A row within 16
    const int fq   = lane >> 4;     // k-subchunk selector
    const int o0   = blockIdx.x * 16;

    // B: lane reads idx[(o0+fr)*2048 + k*32 + fq*8 .. +8)
    const int* bPtr = idx + (long)(o0 + fr) * K_TOT + fq * 8;
    // A: Y2f, mg = wave*4 + mt; frag(mg,kc) at ((mg*64+kc)*64+lane)*8 elems
    const unsigned short* aPtr = Y2f + ((long)(wave * 4) * KSTEPS * 64 + lane) * 8;
    // strides (elements): kc -> 512, mt -> 64*64*8 = 32768

    int4 bLo[DEPTH], bHi[DEPTH];
    bf16x8 aF[2][4];
    f32x4 acc[4] = {{0.f,0.f,0.f,0.f},{0.f,0.f,0.f,0.f},
                    {0.f,0.f,0.f,0.f},{0.f,0.f,0.f,0.f}};

    // prologue: B for k=0..3, A for k=0,1
#pragma unroll
    for (int s = 0; s < DEPTH; ++s) {
        const int* p = bPtr + s * 32;
        bLo[s] = *(const int4*)p;
        bHi[s] = *(const int4*)(p + 4);
    }
#pragma unroll
    for (int mt = 0; mt < 4; ++mt) {
        aF[0][mt] = *(const bf16x8*)(aPtr + mt * 32768);
        aF[1][mt] = *(const bf16x8*)(aPtr + mt * 32768 + 512);
    }

    for (int kc = 0; kc < KSTEPS; kc += DEPTH) {
#pragma unroll
        for (int u = 0; u < DEPTH; ++u) {
            const int k = kc + u;
            bf16x8 bf = cvt_bfrag(bLo[u], bHi[u]);
            if (k + DEPTH < KSTEPS) {           // reissue B depth-4 ahead
                const int* p = bPtr + (k + DEPTH) * 32;
                bLo[u] = *(const int4*)p;
                bHi[u] = *(const int4*)(p + 4);
            }
#pragma unroll
            for (int mt = 0; mt < 4; ++mt)
                acc[mt] = __builtin_amdgcn_mfma_f32_16x16x32_bf16(
                    aF[k & 1][mt], bf, acc[mt], 0, 0, 0);
            if (k + 2 < KSTEPS) {               // reissue A depth-2 ahead
#pragma unroll
                for (int mt = 0; mt < 4; ++mt)
                    aF[k & 1][mt] =
                        *(const bf16x8*)(aPtr + mt * 32768 + (k + 2) * 512);
            }
        }
    }

    // epilogue: D layout col=lane&15, row=(lane>>4)*4+reg
    const int col = o0 + fr;
    const float bv = bias[col];
#pragma unroll
    for (int mt = 0; mt < 4; ++mt) {
        const int row0 = wave * 64 + mt * 16 + fq * 4;
#pragma unroll
        for (int r = 0; r < 4; ++r)
            out[(long)(row0 + r) * N_TOT + col] = acc[mt][r] + bv + corr[row0 + r];
    }
}

extern "C" void kernel_launch(void* const* d_in, const int* in_sizes, int n_in,
                              void* d_out, int out_size, void* d_ws, size_t ws_size,
                              hipStream_t stream) {
    const float* x       = (const float*)d_in[0];   // [32,8,4096]
    const int*   idx     = (const int*)d_in[1];     // [2097152, 8]
    const float* c_min   = (const float*)d_in[2];   // [8]
    const float* c_range = (const float*)d_in[3];   // [8]
    const float* bias    = (const float*)d_in[4];   // [8192]
    float* out = (float*)d_out;                     // [256, 8192]

    unsigned short* Y2f = (unsigned short*)d_ws;                   // 1 MB
    float* corr = (float*)((char*)d_ws + (size_t)256 * K_TOT * 2); // 256 fp32

    prep_kernel<<<256, 256, 0, stream>>>(x, c_min, c_range, Y2f, corr);
    gemm_kernel<<<N_TOT / 16, 256, 0, stream>>>(Y2f, idx, bias, corr, out);
}

// Round 3
// 125.796 us; speedup vs baseline: 1.2032x; 1.1812x over previous
//
#include <hip/hip_runtime.h>

// FreqLinear: out = Y2 @ float(idx)^T + corr[m] + bias[o], K = 2048.
// GEMM v3: grid 256 x 512thr (8 waves), block = 32 cols x 256 rows.
// idx staged per-256-K chunk: global int4 -> regs (issued 1 chunk ahead of
// use) -> cvt bf16 once -> LDS [kstep][fq][col] (conflict-free b128 frags),
// double-buffered. All 16 A-frags of a chunk prefetched up-front (L2-hot)
// so no MFMA waits behind the staging stream in the in-order vmem queue.
// Barriers: raw s_barrier + lgkmcnt(0) only (no vmcnt(0) drain).

typedef __attribute__((ext_vector_type(8))) short bf16x8;   // 8 bf16
typedef __attribute__((ext_vector_type(4))) float f32x4;

#define K_TOT   2048
#define N_TOT   8192
#define NT      32        // cols per block
#define NCHUNK  8         // K chunks of 256
#define SPC     8         // ksteps (K=32) per chunk
#define LDS_CH  16384     // bytes per LDS chunk buffer (8*4*32*16)

__device__ __forceinline__ unsigned short f2bf_rn(float f) {
    unsigned u = __float_as_uint(f);
    u += 0x7FFFu + ((u >> 16) & 1u);
    return (unsigned short)(u >> 16);
}
// two ints (0..255) -> exact floats -> packed bf16 pair (truncation exact)
__device__ __forceinline__ unsigned pack2(int a, int b) {
    unsigned ua = __float_as_uint((float)a);
    unsigned ub = __float_as_uint((float)b);
    return __builtin_amdgcn_perm(ub, ua, 0x07060302u);
}

__device__ __forceinline__ void lds_barrier() {
    asm volatile("" ::: "memory");
    __builtin_amdgcn_s_waitcnt(0xC07F);   // lgkmcnt(0); vmcnt=63, expcnt=7
    __builtin_amdgcn_s_barrier();
    asm volatile("" ::: "memory");
}

// ---------------- Kernel A: build Y2f (bf16, frag order) + corr ------------
__global__ __launch_bounds__(256) void prep_kernel(
    const float* __restrict__ x, const float* __restrict__ c_min,
    const float* __restrict__ c_range, unsigned short* __restrict__ Y2f,
    float* __restrict__ corr)
{
    __shared__ float Bk[8][16];
    __shared__ float scmin[8];
    __shared__ float ss[8];
    __shared__ float red[4];
    const int tid = threadIdx.x;
    const int m = blockIdx.x;
    if (tid < 128) {
        int k = tid >> 4, t = tid & 15;
        float v = cosf(3.14159265358979f * (t + 0.5f) * (float)k / 16.0f)
                  * 0.353553390593274f;                 // sqrt(2/16)
        if (k == 0) v *= 0.707106781186548f;            // 1/sqrt(2)
        Bk[k][t] = v;
    }
    if (tid < 8) {
        scmin[tid] = c_min[tid];
        ss[tid] = c_range[tid] * (1.0f / 255.0f);
    }
    __syncthreads();

    const float* xp = x + (long)m * 4096 + tid * 16;
    float xs[16];
#pragma unroll
    for (int q = 0; q < 4; ++q) {
        float4 v = *(const float4*)(xp + q * 4);
        xs[q * 4 + 0] = v.x; xs[q * 4 + 1] = v.y;
        xs[q * 4 + 2] = v.z; xs[q * 4 + 3] = v.w;
    }
    float partial = 0.0f;
    unsigned short yo[8];
#pragma unroll
    for (int k = 0; k < 8; ++k) {
        float y = 0.0f;
#pragma unroll
        for (int t = 0; t < 16; ++t) y += xs[t] * Bk[k][t];
        partial += y * scmin[k];
        yo[k] = f2bf_rn(y * ss[k]);
    }
    uint4 pk;
    pk.x = (unsigned)yo[0] | ((unsigned)yo[1] << 16);
    pk.y = (unsigned)yo[2] | ((unsigned)yo[3] << 16);
    pk.z = (unsigned)yo[4] | ((unsigned)yo[5] << 16);
    pk.w = (unsigned)yo[6] | ((unsigned)yo[7] << 16);
    // frag-order store: kc = tid>>2, fq = tid&3, mg = m>>4, fr = m&15
    {
        const int mg = m >> 4, fr = m & 15, kc = tid >> 2, fq = tid & 3;
        unsigned short* dst = Y2f + ((long)((mg * 64 + kc) * 64) + fq * 16 + fr) * 8;
        *(uint4*)dst = pk;
    }
#pragma unroll
    for (int off = 32; off > 0; off >>= 1)
        partial += __shfl_down(partial, off, 64);
    if ((tid & 63) == 0) red[tid >> 6] = partial;
    __syncthreads();
    if (tid == 0) corr[m] = red[0] + red[1] + red[2] + red[3];
}

// ---------------- Kernel B ------------------------------------------------
struct Stage { int4 v[4]; };

__global__ __launch_bounds__(512, 2) void gemm_kernel(
    const unsigned short* __restrict__ Y2f, const int* __restrict__ idx,
    const float* __restrict__ bias, const float* __restrict__ corr,
    float* __restrict__ out)
{
    __shared__ char lds[2 * LDS_CH];

    const int tid  = threadIdx.x;
    const int wave = tid >> 6;
    const int lane = tid & 63;
    const int fr   = lane & 15;
    const int fq   = lane >> 4;
    const int o0   = blockIdx.x * NT;

    // staging: l-th load covers col o0 + l*8 + wave, 1KB (256 ints) per chunk
    const int* sBase = idx + (long)(o0 + wave) * K_TOT + lane * 4;
    // LDS dst: elem (col, kq=lane): [(kq>>3)*4 + ((kq&7)>>1)][col], j=(kq&1)*4
    const int dstBase = (((lane >> 3) * 4 + ((lane & 7) >> 1)) * 32 + wave) * 16
                        + (lane & 1) * 8;

    // A: frag(mg, kcg) at bf16x8 index (mg*64 + kcg)*64 + lane; mg = wave*2+mt
    const bf16x8* aB[2];
    aB[0] = (const bf16x8*)Y2f + (long)((wave * 2 + 0) * 64) * 64 + lane;
    aB[1] = (const bf16x8*)Y2f + (long)((wave * 2 + 1) * 64) * 64 + lane;

    f32x4 acc[2][2] = {{{0.f,0.f,0.f,0.f},{0.f,0.f,0.f,0.f}},
                       {{0.f,0.f,0.f,0.f},{0.f,0.f,0.f,0.f}}};

    Stage S[2];

#define STAGE_LOAD(slot, ch)                                              \
    {                                                                     \
        _Pragma("unroll")                                                 \
        for (int l = 0; l < 4; ++l)                                       \
            S[slot].v[l] = *(const int4*)(sBase + l * 8 * K_TOT + (ch) * 256); \
    }

#define STAGE_WRITE(slot, ch)                                             \
    {                                                                     \
        char* buf = lds + ((ch) & 1) * LDS_CH;                            \
        _Pragma("unroll")                                                 \
        for (int l = 0; l < 4; ++l) {                                     \
            uint2 w;                                                      \
            w.x = pack2(S[slot].v[l].x, S[slot].v[l].y);                  \
            w.y = pack2(S[slot].v[l].z, S[slot].v[l].w);                  \
            *(uint2*)(buf + dstBase + l * 128) = w;                       \
        }                                                                 \
    }

#define COMPUTE(ch)                                                       \
    {                                                                     \
        const char* buf = lds + ((ch) & 1) * LDS_CH;                      \
        bf16x8 a[SPC][2];                                                 \
        _Pragma("unroll")                                                 \
        for (int s = 0; s < SPC; ++s) {                                   \
            a[s][0] = aB[0][((ch) * SPC + s) * 64];                       \
            a[s][1] = aB[1][((ch) * SPC + s) * 64];                       \
        }                                                                 \
        bf16x8 b[2][2];                                                   \
        _Pragma("unroll")                                                 \
        for (int g = 0; g < 2; ++g)                                       \
            b[0][g] = *(const bf16x8*)(buf + ((0 * 4 + fq) * 32 + g * 16 + fr) * 16); \
        _Pragma("unroll")                                                 \
        for (int s = 0; s < SPC; ++s) {                                   \
            if (s + 1 < SPC) {                                            \
                _Pragma("unroll")                                         \
                for (int g = 0; g < 2; ++g)                               \
                    b[(s + 1) & 1][g] = *(const bf16x8*)(buf +            \
                        (((s + 1) * 4 + fq) * 32 + g * 16 + fr) * 16);    \
            }                                                             \
            _Pragma("unroll")                                             \
            for (int mt = 0; mt < 2; ++mt) {                              \
                _Pragma("unroll")                                         \
                for (int g = 0; g < 2; ++g)                               \
                    acc[mt][g] = __builtin_amdgcn_mfma_f32_16x16x32_bf16( \
                        a[s][mt], b[s & 1][g], acc[mt][g], 0, 0, 0);      \
            }                                                             \
        }                                                                 \
    }

    // prologue: load chunks 0,1; write 0; barrier
    STAGE_LOAD(0, 0)
    STAGE_LOAD(1, 1)
    STAGE_WRITE(0, 0)
    lds_barrier();

    // steady: compute(c); stage(c+2); write(c+1); barrier     (c = 0..5)
#pragma unroll
    for (int c = 0; c < NCHUNK - 2; ++c) {
        COMPUTE(c)
        STAGE_LOAD(c & 1, c + 2)
        STAGE_WRITE((c + 1) & 1, c + 1)
        lds_barrier();
    }
    // tail: compute(6); write(7); barrier; compute(7)
    COMPUTE(NCHUNK - 2)
    STAGE_WRITE((NCHUNK - 1) & 1, NCHUNK - 1)
    lds_barrier();
    COMPUTE(NCHUNK - 1)

    // epilogue: D layout col=lane&15, row=(lane>>4)*4+reg
#pragma unroll
    for (int mt = 0; mt < 2; ++mt) {
#pragma unroll
        for (int g = 0; g < 2; ++g) {
            const int col = o0 + g * 16 + fr;
            const float bv = bias[col];
#pragma unroll
            for (int r = 0; r < 4; ++r) {
                const int row = (wave * 2 + mt) * 16 + fq * 4 + r;
                out[(long)row * N_TOT + col] = acc[mt][g][r] + bv + corr[row];
            }
        }
    }
#undef STAGE_LOAD
#undef STAGE_WRITE
#undef COMPUTE
}

extern "C" void kernel_launch(void* const* d_in, const int* in_sizes, int n_in,
                              void* d_out, int out_size, void* d_ws, size_t ws_size,
                              hipStream_t stream) {
    const float* x       = (const float*)d_in[0];   // [32,8,4096]
    const int*   idx     = (const int*)d_in[1];     // [2097152, 8]
    const float* c_min   = (const float*)d_in[2];   // [8]
    const float* c_range = (const float*)d_in[3];   // [8]
    const float* bias    = (const float*)d_in[4];   // [8192]
    float* out = (float*)d_out;                     // [256, 8192]

    unsigned short* Y2f = (unsigned short*)d_ws;                   // 1 MB
    float* corr = (float*)((char*)d_ws + (size_t)256 * K_TOT * 2); // 256 fp32

    prep_kernel<<<256, 256, 0, stream>>>(x, c_min, c_range, Y2f, corr);
    gemm_kernel<<<N_TOT / NT, 512, 0, stream>>>(Y2f, idx, bias, corr, out);
}

// Round 4
// 124.519 us; speedup vs baseline: 1.2156x; 1.0103x over previous
//
#include <hip/hip_runtime.h>

// FreqLinear: out = Y2 @ float(idx)^T + corr[m] + bias[o], K = 2048.
// GEMM v4: grid 512 x 256thr (4 waves) = 2 blocks/CU for cross-block overlap
// of the per-chunk HBM drain. Block = 32 cols x 128 rows (half h = bIdx>>8;
// pair b/b+256 shares idx cols -> same XCD -> L2 dedupe). idx staged per
// BK=256 chunk: 8x int4/thread -> cvt bf16 -> XOR-swizzled LDS
//   addr(col,kq) = col*512 + ((kq>>1)^col)*16 + (kq&1)*8
// which is bank-uniform for BOTH k-major writes and col-major b128 frag
// reads (v3's [s][fq][col] layout had ~16-way write conflicts). All 16
// A-frags of a chunk prefetched at compute start (before next stage loads
// enter the in-order vmem queue). Barrier = s_barrier + lgkmcnt(0) only.

typedef __attribute__((ext_vector_type(8))) short bf16x8;   // 8 bf16
typedef __attribute__((ext_vector_type(4))) float f32x4;

#define K_TOT   2048
#define N_TOT   8192
#define NT      32        // cols per block
#define NCHUNK  8         // K chunks of 256
#define SPC     8         // ksteps (K=32) per chunk
#define LDS_CH  16384     // bytes per LDS chunk buffer: 32 cols * 256 * 2B

__device__ __forceinline__ unsigned short f2bf_rn(float f) {
    unsigned u = __float_as_uint(f);
    u += 0x7FFFu + ((u >> 16) & 1u);
    return (unsigned short)(u >> 16);
}
// two ints (0..255) -> exact floats -> packed bf16 pair (truncation exact)
__device__ __forceinline__ unsigned pack2(int a, int b) {
    unsigned ua = __float_as_uint((float)a);
    unsigned ub = __float_as_uint((float)b);
    return __builtin_amdgcn_perm(ub, ua, 0x07060302u);
}

__device__ __forceinline__ void lds_barrier() {
    asm volatile("" ::: "memory");
    __builtin_amdgcn_s_waitcnt(0xC07F);   // lgkmcnt(0); vmcnt=63, expcnt=7
    __builtin_amdgcn_s_barrier();
    asm volatile("" ::: "memory");
}

// ---------------- Kernel A: build Y2f (bf16, frag order) + corr ------------
__global__ __launch_bounds__(256) void prep_kernel(
    const float* __restrict__ x, const float* __restrict__ c_min,
    const float* __restrict__ c_range, unsigned short* __restrict__ Y2f,
    float* __restrict__ corr)
{
    __shared__ float Bk[8][16];
    __shared__ float scmin[8];
    __shared__ float ss[8];
    __shared__ float red[4];
    const int tid = threadIdx.x;
    const int m = blockIdx.x;
    if (tid < 128) {
        int k = tid >> 4, t = tid & 15;
        float v = cosf(3.14159265358979f * (t + 0.5f) * (float)k / 16.0f)
                  * 0.353553390593274f;                 // sqrt(2/16)
        if (k == 0) v *= 0.707106781186548f;            // 1/sqrt(2)
        Bk[k][t] = v;
    }
    if (tid < 8) {
        scmin[tid] = c_min[tid];
        ss[tid] = c_range[tid] * (1.0f / 255.0f);
    }
    __syncthreads();

    const float* xp = x + (long)m * 4096 + tid * 16;
    float xs[16];
#pragma unroll
    for (int q = 0; q < 4; ++q) {
        float4 v = *(const float4*)(xp + q * 4);
        xs[q * 4 + 0] = v.x; xs[q * 4 + 1] = v.y;
        xs[q * 4 + 2] = v.z; xs[q * 4 + 3] = v.w;
    }
    float partial = 0.0f;
    unsigned short yo[8];
#pragma unroll
    for (int k = 0; k < 8; ++k) {
        float y = 0.0f;
#pragma unroll
        for (int t = 0; t < 16; ++t) y += xs[t] * Bk[k][t];
        partial += y * scmin[k];
        yo[k] = f2bf_rn(y * ss[k]);
    }
    uint4 pk;
    pk.x = (unsigned)yo[0] | ((unsigned)yo[1] << 16);
    pk.y = (unsigned)yo[2] | ((unsigned)yo[3] << 16);
    pk.z = (unsigned)yo[4] | ((unsigned)yo[5] << 16);
    pk.w = (unsigned)yo[6] | ((unsigned)yo[7] << 16);
    // frag-order store: kc = tid>>2, fq = tid&3, mg = m>>4, fr = m&15
    {
        const int mg = m >> 4, fr = m & 15, kc = tid >> 2, fq = tid & 3;
        unsigned short* dst = Y2f + ((long)((mg * 64 + kc) * 64) + fq * 16 + fr) * 8;
        *(uint4*)dst = pk;
    }
#pragma unroll
    for (int off = 32; off > 0; off >>= 1)
        partial += __shfl_down(partial, off, 64);
    if ((tid & 63) == 0) red[tid >> 6] = partial;
    __syncthreads();
    if (tid == 0) corr[m] = red[0] + red[1] + red[2] + red[3];
}

// ---------------- Kernel B ------------------------------------------------
__global__ __launch_bounds__(256, 2) void gemm_kernel(
    const unsigned short* __restrict__ Y2f, const int* __restrict__ idx,
    const float* __restrict__ bias, const float* __restrict__ corr,
    float* __restrict__ out)
{
    __shared__ char lds[2 * LDS_CH];

    const int tid  = threadIdx.x;
    const int wave = tid >> 6;
    const int lane = tid & 63;
    const int fr   = lane & 15;
    const int fq   = lane >> 4;
    const int o0   = (blockIdx.x & 255) * NT;
    const int h    = blockIdx.x >> 8;         // m-half: rows [h*128, h*128+128)

    // staging: load l covers local col (wave + l*4), lane covers int-quad kq=lane
    const int* sBase = idx + (long)(o0 + wave) * K_TOT + lane * 4;
    // LDS write addr (per local col c): c*512 + ((lane>>1)^c)*16 + (lane&1)*8
    const int wslot = lane >> 1;
    const int wj    = (lane & 1) * 8;

    // A frags: mg = h*8 + wave*2 + mt; frag(mg,kc) at bf16x8 idx (mg*64+kc)*64+lane
    const bf16x8* aF[2];
    aF[0] = (const bf16x8*)Y2f + (long)((h * 8 + wave * 2 + 0) * 64) * 64 + lane;
    aF[1] = (const bf16x8*)Y2f + (long)((h * 8 + wave * 2 + 1) * 64) * 64 + lane;

    f32x4 acc[2][2] = {{{0.f,0.f,0.f,0.f},{0.f,0.f,0.f,0.f}},
                       {{0.f,0.f,0.f,0.f},{0.f,0.f,0.f,0.f}}};
    int4 S[8];

#define STAGE_LOAD(ch)                                                    \
    {                                                                     \
        _Pragma("unroll")                                                 \
        for (int l = 0; l < 8; ++l)                                       \
            S[l] = *(const int4*)(sBase + (long)l * 4 * K_TOT + (ch) * 256); \
    }

#define STAGE_WRITE(ch)                                                   \
    {                                                                     \
        char* buf = lds + ((ch) & 1) * LDS_CH;                            \
        _Pragma("unroll")                                                 \
        for (int l = 0; l < 8; ++l) {                                     \
            const int c = wave + l * 4;                                   \
            uint2 w;                                                      \
            w.x = pack2(S[l].x, S[l].y);                                  \
            w.y = pack2(S[l].z, S[l].w);                                  \
            *(uint2*)(buf + c * 512 + ((wslot ^ c) * 16) + wj) = w;       \
        }                                                                 \
    }

#define BREAD(buf, s, g)                                                  \
    (*(const bf16x8*)((buf) + (g * 16 + fr) * 512 +                       \
                      ((((s) * 4 + fq) ^ (g * 16 + fr)) * 16)))

#define COMPUTE(ch)                                                       \
    {                                                                     \
        const char* buf = lds + ((ch) & 1) * LDS_CH;                      \
        bf16x8 a[SPC][2];                                                 \
        _Pragma("unroll")                                                 \
        for (int s = 0; s < SPC; ++s) {                                   \
            a[s][0] = aF[0][((ch) * SPC + s) * 64];                       \
            a[s][1] = aF[1][((ch) * SPC + s) * 64];                       \
        }                                                                 \
        bf16x8 b[2][2];                                                   \
        b[0][0] = BREAD(buf, 0, 0);                                       \
        b[0][1] = BREAD(buf, 0, 1);                                       \
        _Pragma("unroll")                                                 \
        for (int s = 0; s < SPC; ++s) {                                   \
            if (s + 1 < SPC) {                                            \
                b[(s + 1) & 1][0] = BREAD(buf, (s + 1), 0);               \
                b[(s + 1) & 1][1] = BREAD(buf, (s + 1), 1);               \
            }                                                             \
            _Pragma("unroll")                                             \
            for (int mt = 0; mt < 2; ++mt)                                \
                _Pragma("unroll")                                         \
                for (int g = 0; g < 2; ++g)                               \
                    acc[mt][g] = __builtin_amdgcn_mfma_f32_16x16x32_bf16( \
                        a[s][mt], b[s & 1][g], acc[mt][g], 0, 0, 0);      \
        }                                                                 \
    }

    // prologue: S<-0; write(0); S<-1; barrier
    STAGE_LOAD(0)
    STAGE_WRITE(0)
    STAGE_LOAD(1)
    lds_barrier();

    // steady: compute(c); write(c+1); S<-(c+2); barrier      (c = 0..5)
#pragma unroll
    for (int c = 0; c < NCHUNK - 2; ++c) {
        COMPUTE(c)
        STAGE_WRITE(c + 1)
        STAGE_LOAD(c + 2)
        lds_barrier();
    }
    // tail: compute(6); write(7); barrier; compute(7)
    COMPUTE(NCHUNK - 2)
    STAGE_WRITE(NCHUNK - 1)
    lds_barrier();
    COMPUTE(NCHUNK - 1)

    // epilogue: D layout col=lane&15, row=(lane>>4)*4+reg
#pragma unroll
    for (int mt = 0; mt < 2; ++mt) {
#pragma unroll
        for (int g = 0; g < 2; ++g) {
            const int col = o0 + g * 16 + fr;
            const float bv = bias[col];
            const int row0 = (h * 8 + wave * 2 + mt) * 16 + fq * 4;
#pragma unroll
            for (int r = 0; r < 4; ++r)
                out[(long)(row0 + r) * N_TOT + col] =
                    acc[mt][g][r] + bv + corr[row0 + r];
        }
    }
#undef STAGE_LOAD
#undef STAGE_WRITE
#undef BREAD
#undef COMPUTE
}

extern "C" void kernel_launch(void* const* d_in, const int* in_sizes, int n_in,
                              void* d_out, int out_size, void* d_ws, size_t ws_size,
                              hipStream_t stream) {
    const float* x       = (const float*)d_in[0];   // [32,8,4096]
    const int*   idx     = (const int*)d_in[1];     // [2097152, 8]
    const float* c_min   = (const float*)d_in[2];   // [8]
    const float* c_range = (const float*)d_in[3];   // [8]
    const float* bias    = (const float*)d_in[4];   // [8192]
    float* out = (float*)d_out;                     // [256, 8192]

    unsigned short* Y2f = (unsigned short*)d_ws;                   // 1 MB
    float* corr = (float*)((char*)d_ws + (size_t)256 * K_TOT * 2); // 256 fp32

    prep_kernel<<<256, 256, 0, stream>>>(x, c_min, c_range, Y2f, corr);
    gemm_kernel<<<512, 256, 0, stream>>>(Y2f, idx, bias, corr, out);
}

// Round 5
// 119.333 us; speedup vs baseline: 1.2684x; 1.0435x over previous
//
#include <hip/hip_runtime.h>

// FreqLinear: out = Y2 @ float(idx)^T + corr[m] + bias[o], K = 2048.
// GEMM v5: B-RESIDENT LDS. grid 256 x 512thr (8 waves), block = 32 cols x
// all 256 rows. The block's whole B operand (32x2048 bf16 = 128 KB) lives in
// LDS; each 256-K chunk region is written once, never evicted, so staging
// never waits on consumers. Per-iteration order:
//    A_burst(c) -> idx_load(c+2) -> write(c+1) -> barrier -> MFMA(c)
// keeps A-frag vmcnt waits AHEAD of the HBM idx stream (wait = vmcnt(4),
// the idx loads stay in flight across chunks; 2-deep = 8 KB/wave, 64 KB/CU
// outstanding >> needed to saturate this CU's HBM share). One barrier per
// chunk (s_barrier + lgkmcnt(0) only, no vmcnt drain).

typedef __attribute__((ext_vector_type(8))) short bf16x8;   // 8 bf16
typedef __attribute__((ext_vector_type(4))) float f32x4;

#define K_TOT   2048
#define N_TOT   8192
#define NT      32        // cols per block
#define NCHUNK  8         // K chunks of 256
#define SPC     8         // ksteps (K=32) per chunk
#define LDS_CH  16384     // bytes per chunk region: 32 cols * 256 * 2B

__device__ __forceinline__ unsigned short f2bf_rn(float f) {
    unsigned u = __float_as_uint(f);
    u += 0x7FFFu + ((u >> 16) & 1u);
    return (unsigned short)(u >> 16);
}
// two ints (0..255) -> exact floats -> packed bf16 pair (truncation exact)
__device__ __forceinline__ unsigned pack2(int a, int b) {
    unsigned ua = __float_as_uint((float)a);
    unsigned ub = __float_as_uint((float)b);
    return __builtin_amdgcn_perm(ub, ua, 0x07060302u);
}

__device__ __forceinline__ void lds_barrier() {
    asm volatile("" ::: "memory");
    __builtin_amdgcn_s_waitcnt(0xC07F);   // lgkmcnt(0); vmcnt=63, expcnt=7
    __builtin_amdgcn_s_barrier();
    asm volatile("" ::: "memory");
}

// ---------------- Kernel A: build Y2f (bf16, frag order) + corr ------------
__global__ __launch_bounds__(256) void prep_kernel(
    const float* __restrict__ x, const float* __restrict__ c_min,
    const float* __restrict__ c_range, unsigned short* __restrict__ Y2f,
    float* __restrict__ corr)
{
    __shared__ float Bk[8][16];
    __shared__ float scmin[8];
    __shared__ float ss[8];
    __shared__ float red[4];
    const int tid = threadIdx.x;
    const int m = blockIdx.x;
    if (tid < 128) {
        int k = tid >> 4, t = tid & 15;
        float v = cosf(3.14159265358979f * (t + 0.5f) * (float)k / 16.0f)
                  * 0.353553390593274f;                 // sqrt(2/16)
        if (k == 0) v *= 0.707106781186548f;            // 1/sqrt(2)
        Bk[k][t] = v;
    }
    if (tid < 8) {
        scmin[tid] = c_min[tid];
        ss[tid] = c_range[tid] * (1.0f / 255.0f);
    }
    __syncthreads();

    const float* xp = x + (long)m * 4096 + tid * 16;
    float xs[16];
#pragma unroll
    for (int q = 0; q < 4; ++q) {
        float4 v = *(const float4*)(xp + q * 4);
        xs[q * 4 + 0] = v.x; xs[q * 4 + 1] = v.y;
        xs[q * 4 + 2] = v.z; xs[q * 4 + 3] = v.w;
    }
    float partial = 0.0f;
    unsigned short yo[8];
#pragma unroll
    for (int k = 0; k < 8; ++k) {
        float y = 0.0f;
#pragma unroll
        for (int t = 0; t < 16; ++t) y += xs[t] * Bk[k][t];
        partial += y * scmin[k];
        yo[k] = f2bf_rn(y * ss[k]);
    }
    uint4 pk;
    pk.x = (unsigned)yo[0] | ((unsigned)yo[1] << 16);
    pk.y = (unsigned)yo[2] | ((unsigned)yo[3] << 16);
    pk.z = (unsigned)yo[4] | ((unsigned)yo[5] << 16);
    pk.w = (unsigned)yo[6] | ((unsigned)yo[7] << 16);
    // frag-order store: kc = tid>>2, fq = tid&3, mg = m>>4, fr = m&15
    {
        const int mg = m >> 4, fr = m & 15, kc = tid >> 2, fq = tid & 3;
        unsigned short* dst = Y2f + ((long)((mg * 64 + kc) * 64) + fq * 16 + fr) * 8;
        *(uint4*)dst = pk;
    }
#pragma unroll
    for (int off = 32; off > 0; off >>= 1)
        partial += __shfl_down(partial, off, 64);
    if ((tid & 63) == 0) red[tid >> 6] = partial;
    __syncthreads();
    if (tid == 0) corr[m] = red[0] + red[1] + red[2] + red[3];
}

// ---------------- Kernel B ------------------------------------------------
__global__ __launch_bounds__(512, 2) void gemm_kernel(
    const unsigned short* __restrict__ Y2f, const int* __restrict__ idx,
    const float* __restrict__ bias, const float* __restrict__ corr,
    float* __restrict__ out)
{
    __shared__ char lds[NCHUNK * LDS_CH];     // 128 KB, B-resident

    const int tid  = threadIdx.x;
    const int wave = tid >> 6;
    const int lane = tid & 63;
    const int fr   = lane & 15;
    const int fq   = lane >> 4;
    const int o0   = blockIdx.x * NT;

    // staging: thread -> col scol, int-quads skq + r*16 (r = 0..3)
    const int scol = tid >> 4;      // 0..31
    const int skq  = tid & 15;      // 0..15
    const int* sBase = idx + (long)(o0 + scol) * K_TOT + skq * 4;

    // A frags: mg = wave*2 + mt; frag(mg,kc) at bf16x8 index (mg*64+kc)*64+lane
    const bf16x8* aF[2];
    aF[0] = (const bf16x8*)Y2f + (long)((wave * 2 + 0) * 64) * 64 + lane;
    aF[1] = (const bf16x8*)Y2f + (long)((wave * 2 + 1) * 64) * 64 + lane;

    f32x4 acc[2][2] = {{{0.f,0.f,0.f,0.f},{0.f,0.f,0.f,0.f}},
                       {{0.f,0.f,0.f,0.f},{0.f,0.f,0.f,0.f}}};
    int4 S[2][4];    // 2 chunks in flight

#define STAGE_LOAD(ch)                                                    \
    {                                                                     \
        _Pragma("unroll")                                                 \
        for (int r = 0; r < 4; ++r)                                       \
            S[(ch) & 1][r] = *(const int4*)(sBase + (ch) * 256 + r * 64); \
    }

    // XOR-swizzled chunk region: addr(col, kq) = col*512 + ((kq>>1)^col)*16
    //                                            + (kq&1)*8   (kq = int-quad)
#define STAGE_WRITE(ch)                                                   \
    {                                                                     \
        char* buf = lds + (ch) * LDS_CH;                                  \
        _Pragma("unroll")                                                 \
        for (int r = 0; r < 4; ++r) {                                     \
            const int kq = skq + r * 16;                                  \
            uint2 w;                                                      \
            w.x = pack2(S[(ch) & 1][r].x, S[(ch) & 1][r].y);              \
            w.y = pack2(S[(ch) & 1][r].z, S[(ch) & 1][r].w);              \
            *(uint2*)(buf + scol * 512 + (((kq >> 1) ^ scol) * 16)        \
                      + (kq & 1) * 8) = w;                                \
        }                                                                 \
    }

#define BREAD(buf, s, g)                                                  \
    (*(const bf16x8*)((buf) + (g * 16 + fr) * 512 +                       \
                      ((((s) * 4 + fq) ^ (g * 16 + fr)) * 16)))

    // prologue: stream chunks 0,1; write 0; barrier
    STAGE_LOAD(0)
    STAGE_LOAD(1)
    STAGE_WRITE(0)
    lds_barrier();

#pragma unroll
    for (int c = 0; c < NCHUNK; ++c) {
        // 1) A-burst for chunk c (L2-hot) -- BEFORE new HBM loads, so MFMA
        //    waits (vmcnt(4)) never drain the idx stream
        bf16x8 a[SPC][2];
#pragma unroll
        for (int s = 0; s < SPC; ++s) {
            a[s][0] = aF[0][(c * SPC + s) * 64];
            a[s][1] = aF[1][(c * SPC + s) * 64];
        }
        // 2) keep the idx stream 2 chunks deep
        if (c + 2 < NCHUNK) STAGE_LOAD(c + 2)
        // 3) publish chunk c+1
        if (c + 1 < NCHUNK) STAGE_WRITE(c + 1)
        lds_barrier();
        // 4) compute chunk c (region c is immutable from here on)
        {
            const char* buf = lds + c * LDS_CH;
            bf16x8 b[2][2];
            b[0][0] = BREAD(buf, 0, 0);
            b[0][1] = BREAD(buf, 0, 1);
#pragma unroll
            for (int s = 0; s < SPC; ++s) {
                if (s + 1 < SPC) {
                    b[(s + 1) & 1][0] = BREAD(buf, (s + 1), 0);
                    b[(s + 1) & 1][1] = BREAD(buf, (s + 1), 1);
                }
#pragma unroll
                for (int mt = 0; mt < 2; ++mt)
#pragma unroll
                    for (int g = 0; g < 2; ++g)
                        acc[mt][g] = __builtin_amdgcn_mfma_f32_16x16x32_bf16(
                            a[s][mt], b[s & 1][g], acc[mt][g], 0, 0, 0);
            }
        }
    }

    // epilogue: D layout col=lane&15, row=(lane>>4)*4+reg
#pragma unroll
    for (int mt = 0; mt < 2; ++mt) {
#pragma unroll
        for (int g = 0; g < 2; ++g) {
            const int col = o0 + g * 16 + fr;
            const float bv = bias[col];
            const int row0 = (wave * 2 + mt) * 16 + fq * 4;
#pragma unroll
            for (int r = 0; r < 4; ++r)
                out[(long)(row0 + r) * N_TOT + col] =
                    acc[mt][g][r] + bv + corr[row0 + r];
        }
    }
#undef STAGE_LOAD
#undef STAGE_WRITE
#undef BREAD
}

extern "C" void kernel_launch(void* const* d_in, const int* in_sizes, int n_in,
                              void* d_out, int out_size, void* d_ws, size_t ws_size,
                              hipStream_t stream) {
    const float* x       = (const float*)d_in[0];   // [32,8,4096]
    const int*   idx     = (const int*)d_in[1];     // [2097152, 8]
    const float* c_min   = (const float*)d_in[2];   // [8]
    const float* c_range = (const float*)d_in[3];   // [8]
    const float* bias    = (const float*)d_in[4];   // [8192]
    float* out = (float*)d_out;                     // [256, 8192]

    unsigned short* Y2f = (unsigned short*)d_ws;                   // 1 MB
    float* corr = (float*)((char*)d_ws + (size_t)256 * K_TOT * 2); // 256 fp32

    prep_kernel<<<256, 256, 0, stream>>>(x, c_min, c_range, Y2f, corr);
    gemm_kernel<<<256, 512, 0, stream>>>(Y2f, idx, bias, corr, out);
}